// Round 5
// baseline (789.790 us; speedup 1.0000x reference)
//
#include <hip/hip_runtime.h>
#include <hip/hip_cooperative_groups.h>

namespace cg = cooperative_groups;

#define NUM_GRID_NODES 262144
#define NUM_MESH_NODES 40962
#define EMBED 64
#define NUM_EDGES 1048576
#define BATCH 4

#define NBLK 1024
#define NTHR 256
#define SCAN_CHUNK 256
#define NCHUNK ((NUM_MESH_NODES + SCAN_CHUNK - 1) / SCAN_CHUNK)  // 161

// ws layout: cursor[40962] | offsets[40963] | sorted_src[1048576] | bsum[161]

__global__ __launch_bounds__(NTHR, 4) void fused_kernel(
    const float* __restrict__ gfeat,
    const int* __restrict__ edge_index,
    int* __restrict__ cursor,
    int* __restrict__ offsets,
    int* __restrict__ sorted_src,
    int* __restrict__ bsum,
    float* __restrict__ out)
{
    cg::grid_group gg = cg::this_grid();
    const int tid = (int)(blockIdx.x * blockDim.x + threadIdx.x);  // 0..262143
    const int lane = (int)threadIdx.x & 63;
    const int wid = (int)threadIdx.x >> 6;

    __shared__ int wsums[4];
    __shared__ int red[4];

    // ---- P0: zero cursor ----
    if (tid < NUM_MESH_NODES) cursor[tid] = 0;
    gg.sync();

    // ---- P1: histogram of dst (4 edges/thread, exact cover: 262144*4 = 1M) ----
    {
        const int e0 = tid * 4;
        int4 a = *reinterpret_cast<const int4*>(&edge_index[2 * e0]);
        int4 b = *reinterpret_cast<const int4*>(&edge_index[2 * e0 + 4]);
        atomicAdd(&cursor[a.y], 1);
        atomicAdd(&cursor[a.w], 1);
        atomicAdd(&cursor[b.y], 1);
        atomicAdd(&cursor[b.w], 1);
    }
    gg.sync();

    // ---- P2a: per-chunk local exclusive scan + chunk totals ----
    if (blockIdx.x < NCHUNK) {
        const int i = (int)blockIdx.x * SCAN_CHUNK + (int)threadIdx.x;
        const int v = (i < NUM_MESH_NODES) ? cursor[i] : 0;
        int incl = v;
        for (int d = 1; d < 64; d <<= 1) {
            int t = __shfl_up(incl, d, 64);
            if (lane >= d) incl += t;
        }
        if (lane == 63) wsums[wid] = incl;
        __syncthreads();
        int wbase = 0;
        for (int w = 0; w < wid; ++w) wbase += wsums[w];
        const int excl = wbase + incl - v;
        if (i < NUM_MESH_NODES) offsets[i] = excl;  // no global base yet
        if (threadIdx.x == NTHR - 1) bsum[blockIdx.x] = wbase + incl;  // chunk total
    }
    gg.sync();

    // ---- P2b: add global chunk base (each chunk-block redundantly reduces bsum[0..c)) ----
    if (blockIdx.x < NCHUNK) {
        int c = ((int)threadIdx.x < (int)blockIdx.x) ? bsum[threadIdx.x] : 0;  // NCHUNK<=256
        for (int d = 32; d > 0; d >>= 1) c += __shfl_down(c, d, 64);
        if (lane == 0) red[wid] = c;
        __syncthreads();
        const int base = red[0] + red[1] + red[2] + red[3];
        const int i = (int)blockIdx.x * SCAN_CHUNK + (int)threadIdx.x;
        if (i < NUM_MESH_NODES) {
            const int o = offsets[i] + base;
            offsets[i] = o;
            cursor[i] = o;
        }
        if (blockIdx.x == 0 && threadIdx.x == 0) offsets[NUM_MESH_NODES] = NUM_EDGES;
    }
    gg.sync();

    // ---- P3: scatter src ids into dst-sorted order ----
    {
        const int e0 = tid * 4;
        int4 a = *reinterpret_cast<const int4*>(&edge_index[2 * e0]);
        int4 b = *reinterpret_cast<const int4*>(&edge_index[2 * e0 + 4]);
        sorted_src[atomicAdd(&cursor[a.y], 1)] = a.x;
        sorted_src[atomicAdd(&cursor[a.w], 1)] = a.z;
        sorted_src[atomicAdd(&cursor[b.y], 1)] = b.x;
        sorted_src[atomicAdd(&cursor[b.w], 1)] = b.z;
    }
    gg.sync();

    // ---- P4: aggregate. wave = (node, batch); batch pinned per XCD pair ----
    {
        const int m = (int)blockIdx.x & 7;
        const int batch = m >> 1;                               // XCDs {2b, 2b+1}
        const int ng = (((int)blockIdx.x >> 3) << 1) + (m & 1); // 0..255 within batch
        const float* gb = gfeat + (size_t)batch * NUM_GRID_NODES * EMBED + lane;
        float* ob = out + (size_t)batch * NUM_MESH_NODES * EMBED + lane;

        for (int node = ng * 4 + wid; node < NUM_MESH_NODES; node += 1024) {
            const int beg = offsets[node];
            const int end = offsets[node + 1];
            float a0 = 0.f, a1 = 0.f, a2 = 0.f, a3 = 0.f;
            float a4 = 0.f, a5 = 0.f, a6 = 0.f, a7 = 0.f;
            int e = beg;
            for (; e + 8 <= end; e += 8) {
                int s0 = sorted_src[e + 0], s1 = sorted_src[e + 1];
                int s2 = sorted_src[e + 2], s3 = sorted_src[e + 3];
                int s4 = sorted_src[e + 4], s5 = sorted_src[e + 5];
                int s6 = sorted_src[e + 6], s7 = sorted_src[e + 7];
                a0 += gb[(size_t)s0 * EMBED];
                a1 += gb[(size_t)s1 * EMBED];
                a2 += gb[(size_t)s2 * EMBED];
                a3 += gb[(size_t)s3 * EMBED];
                a4 += gb[(size_t)s4 * EMBED];
                a5 += gb[(size_t)s5 * EMBED];
                a6 += gb[(size_t)s6 * EMBED];
                a7 += gb[(size_t)s7 * EMBED];
            }
            for (; e < end; ++e) {
                a0 += gb[(size_t)sorted_src[e] * EMBED];
            }
            const float acc = ((a0 + a1) + (a2 + a3)) + ((a4 + a5) + (a6 + a7));
            const float inv = 1.0f / fmaxf((float)(end - beg), 1.0f);
            ob[(size_t)node * EMBED] = acc * inv;
        }
    }
}

extern "C" void kernel_launch(void* const* d_in, const int* in_sizes, int n_in,
                              void* d_out, int out_size, void* d_ws, size_t ws_size,
                              hipStream_t stream) {
    const float* gfeat = (const float*)d_in[0];
    const int* edge_index = (const int*)d_in[1];
    float* out = (float*)d_out;

    int* cursor = (int*)d_ws;
    int* offsets = cursor + NUM_MESH_NODES;
    int* sorted_src = offsets + (NUM_MESH_NODES + 1);
    int* bsum = sorted_src + NUM_EDGES;

    void* args[] = {(void*)&gfeat, (void*)&edge_index, (void*)&cursor,
                    (void*)&offsets, (void*)&sorted_src, (void*)&bsum, (void*)&out};
    hipLaunchCooperativeKernel((const void*)fused_kernel, dim3(NBLK), dim3(NTHR),
                               args, 0, stream);
}

// Round 7
// 213.404 us; speedup vs baseline: 3.7009x; 3.7009x over previous
//
#include <hip/hip_runtime.h>

#define NUM_GRID_NODES 262144
#define NUM_MESH_NODES 40962
#define EMBED 64
#define NUM_EDGES 1048576
#define BATCH 4
#define CAP 80  // max bucket capacity; avg degree 25.6, sigma 5.1 -> P(deg>=80) ~ 1e-19

// ws layout: counts[40962] | slots[40962*80]

// --- Kernel 1: bucket edges by dst in ONE pass (replaces count+scan+permute).
//     4 edges/thread via 2x int4 loads. ---
__global__ void bucket_kernel(const int* __restrict__ edge_index,
                              int* __restrict__ counts,
                              int* __restrict__ slots) {
    int t = blockIdx.x * blockDim.x + threadIdx.x;
    int e0 = t * 4;
    if (e0 < NUM_EDGES) {  // NUM_EDGES % 4 == 0
        int4 a = *reinterpret_cast<const int4*>(&edge_index[2 * e0]);
        int4 b = *reinterpret_cast<const int4*>(&edge_index[2 * e0 + 4]);
        int p0 = atomicAdd(&counts[a.y], 1);
        if (p0 < CAP) slots[a.y * CAP + p0] = a.x;
        int p1 = atomicAdd(&counts[a.w], 1);
        if (p1 < CAP) slots[a.w * CAP + p1] = a.z;
        int p2 = atomicAdd(&counts[b.y], 1);
        if (p2 < CAP) slots[b.y * CAP + p2] = b.x;
        int p3 = atomicAdd(&counts[b.w], 1);
        if (p3 < CAP) slots[b.w * CAP + p3] = b.z;
    }
}

// --- Kernel 2: wave = one (node, batch); batch pinned to an XCD pair via
//     blockIdx%8 round-robin -> each XCD L2 sees one batch's 10.5 MB hot set.
//     Non-temporal output stores keep the streamed 42 MB out of the hot L2. ---
__global__ void aggregate_kernel(const float* __restrict__ grid,
                                 const int* __restrict__ counts,
                                 const int* __restrict__ slots,
                                 float* __restrict__ out) {
    const int m = (int)blockIdx.x & 7;
    const int batch = m >> 1;                              // XCDs {2b, 2b+1}
    const int local = (((int)blockIdx.x >> 3) << 1) + (m & 1);
    const int node = local * 4 + ((int)threadIdx.x >> 6);  // 4 waves/block
    const int lane = (int)threadIdx.x & 63;
    if (node >= NUM_MESH_NODES) return;

    const int cnt = counts[node];
    const int* sl = &slots[node * CAP];
    const float* gb = grid + (size_t)batch * NUM_GRID_NODES * EMBED + lane;

    float a0 = 0.f, a1 = 0.f, a2 = 0.f, a3 = 0.f;
    float a4 = 0.f, a5 = 0.f, a6 = 0.f, a7 = 0.f;
    int e = 0;
    for (; e + 8 <= cnt; e += 8) {
        int s0 = sl[e + 0], s1 = sl[e + 1], s2 = sl[e + 2], s3 = sl[e + 3];
        int s4 = sl[e + 4], s5 = sl[e + 5], s6 = sl[e + 6], s7 = sl[e + 7];
        a0 += gb[(size_t)s0 * EMBED];
        a1 += gb[(size_t)s1 * EMBED];
        a2 += gb[(size_t)s2 * EMBED];
        a3 += gb[(size_t)s3 * EMBED];
        a4 += gb[(size_t)s4 * EMBED];
        a5 += gb[(size_t)s5 * EMBED];
        a6 += gb[(size_t)s6 * EMBED];
        a7 += gb[(size_t)s7 * EMBED];
    }
    for (; e < cnt; ++e) {
        a0 += gb[(size_t)sl[e] * EMBED];
    }
    const float acc = ((a0 + a1) + (a2 + a3)) + ((a4 + a5) + (a6 + a7));
    const float inv = 1.0f / fmaxf((float)cnt, 1.0f);
    float* o = out + ((size_t)batch * NUM_MESH_NODES + (size_t)node) * EMBED + lane;
    __builtin_nontemporal_store(acc * inv, o);
}

extern "C" void kernel_launch(void* const* d_in, const int* in_sizes, int n_in,
                              void* d_out, int out_size, void* d_ws, size_t ws_size,
                              hipStream_t stream) {
    const float* grid = (const float*)d_in[0];
    const int* edge_index = (const int*)d_in[1];
    float* out = (float*)d_out;

    int* counts = (int*)d_ws;
    int* slots = counts + NUM_MESH_NODES;

    hipMemsetAsync(counts, 0, (size_t)NUM_MESH_NODES * sizeof(int), stream);

    const int quad_blocks = (NUM_EDGES / 4 + 255) / 256;  // 1024
    bucket_kernel<<<quad_blocks, 256, 0, stream>>>(edge_index, counts, slots);

    // grid divisible by 8; per-batch node supply = (grid/8)*2*4 >= 40962
    const int agg_grid = 40968;
    aggregate_kernel<<<agg_grid, 256, 0, stream>>>(grid, counts, slots, out);
}